// Round 2
// baseline (508.738 us; speedup 1.0000x reference)
//
#include <hip/hip_runtime.h>
#include <hip/hip_bf16.h>
#include <math.h>

// Problem constants
#define BB 4
#define SS 2048
#define DD 1024
#define HH 16
#define HD 64

#define NEG_BIG (-1e30f)  // finite "-inf": exp(NEG_BIG - m) == 0

// Verified facts (rounds 0-7):
//  - float inputs are fp32; OUTPUT is fp32
//  - MFMA C/D layout col=lane&15, row=quad*4+reg (HW-verified r6)
//  - ws_size >= 2*NE shorts = 33.5 MB (in use, passing)
//  - r7: cvt_pk + ones-MFMA softmax denom + no mid-barrier attn: 575->504us;
//    GEMMs barely moved => staging ROUND-TRIP bound, not cvt-bound.
// Round 8: activations pre-converted to bf16; GEMM big operand staged via
//  global_load_lds (16B, zero VALU); weights stay fp32 reg-cvt (L2-hot);
//  XCD swizzle groups A-panel sharers per XCD; Q+K projections fused (z-dim).

typedef short v8s __attribute__((ext_vector_type(8)));
typedef float v4f __attribute__((ext_vector_type(4)));

__device__ inline unsigned cvt_pk_bf16(float lo, float hi) {
    unsigned r;
    asm("v_cvt_pk_bf16_f32 %0, %1, %2" : "=v"(r) : "v"(lo), "v"(hi));
    return r;
}

__device__ inline short f2bf(float f) {
    return (short)cvt_pk_bf16(f, f);  // low 16 bits = bf16(lo)
}

__device__ inline v4f v4f_zero() {
    v4f z;
    z[0] = 0.f; z[1] = 0.f; z[2] = 0.f; z[3] = 0.f;
    return z;
}

// Convert 8 consecutive fp32 elements to a bf16x8 fragment (4x cvt_pk).
__device__ inline v8s load8f(const float* p) {
    v4f a = *(const v4f*)p;
    v4f b = *(const v4f*)(p + 4);
    union { unsigned u[4]; v8s s; } x;
    x.u[0] = cvt_pk_bf16(a[0], a[1]);
    x.u[1] = cvt_pk_bf16(a[2], a[3]);
    x.u[2] = cvt_pk_bf16(b[0], b[1]);
    x.u[3] = cvt_pk_bf16(b[2], b[3]);
    return x.s;
}

// Async global->LDS, 16B per lane. LDS dest must be wave-uniform base;
// HW scatters lane i to base + i*16B. Global src is per-lane.
__device__ inline void gll16(const void* g, void* l) {
    __builtin_amdgcn_global_load_lds(
        (const __attribute__((address_space(1))) unsigned*)g,
        (__attribute__((address_space(3))) unsigned*)l, 16, 0, 0);
}

// ---------------------------------------------------------------------------
// fp32 -> bf16 elementwise (vectorized, grid-stride). n8 = elems/8.
// ---------------------------------------------------------------------------
__global__ __launch_bounds__(256) void conv_bf16_kernel(
    const float* __restrict__ in, short* __restrict__ out, int n8) {
    int i = blockIdx.x * 256 + threadIdx.x;
    const int stride = gridDim.x * 256;
    for (; i < n8; i += stride) {
        *((v8s*)out + i) = load8f(in + (size_t)i * 8);
    }
}

// ---------------------------------------------------------------------------
// NT GEMM: C[M,N] = A[M,K] * B[N,K]^T + bias, fp32 accum, bf16 MFMA. K=1024.
// The BIG operand is bf16 in global, staged via global_load_lds (no VALU).
// The SMALL operand (weights) is fp32, reg-staged with cvt_pk.
// MODE 0: A big bf16 [M,1024]; C bf16 [B,H,S,HD]. grid (8,64,2) fused Q+K.
// MODE 1: B big bf16 [N,1024] (tokens); A = W fp32; C bf16 [B,H,HD,S]. (64,8)
// MODE 3: A big bf16 ws [B,H,S,HD] remap; C fp32 row-major. grid (8,64).
// Tiles: BM=BN=128, BK=32. 256 thr = 4 waves (2x2), 64x64 per wave.
// XCD swizzle (modes 0/3): same-m0 blocks -> same XCD (A-panel L2 reuse).
// ---------------------------------------------------------------------------
template <int MODE>
__global__ __launch_bounds__(256) void gemm_kernel(
    const void* __restrict__ Pbig, const float* __restrict__ Psml,
    const float* __restrict__ Pbias, void* __restrict__ PC,
    const void* __restrict__ Pbig2, const float* __restrict__ Psml2,
    const float* __restrict__ Pbias2, void* __restrict__ PC2) {
    __shared__ short sA[128 * 32];
    __shared__ short sB[128 * 32];

    const int tid = threadIdx.x;
    const int lane = tid & 63;
    const int wave = tid >> 6;
    const int quad = lane >> 4;
    const int l16 = lane & 15;
    const int wm = wave >> 1;
    const int wn = wave & 1;

    const void* Big = Pbig;
    const float* Sml = Psml;
    const float* bias = Pbias;
    void* Cv = PC;
    if (MODE == 0 && blockIdx.z == 1) {
        Big = Pbig2; Sml = Psml2; bias = Pbias2; Cv = PC2;
    }

    int bx = blockIdx.x, by = blockIdx.y;
    if (MODE != 1) {
        // bijective XCD swizzle: 512 blocks, 8 XCDs, gridDim.x == 8
        int b = bx + (by << 3);
        int l = ((b & 7) << 6) + (b >> 3);
        bx = l & 7;
        by = l >> 3;
    }
    const int m0 = by * 128;
    const int n0 = bx * 128;

    // --- global_load_lds addressing for the big operand ---
    short* sBig = (MODE == 1) ? sB : sA;  // big operand's LDS tile
    short* sSml = (MODE == 1) ? sA : sB;
    const int grow = (wave << 5) + (lane >> 2);  // row within tile (q adds 16)
    const int gcol = (lane & 3) << 3;            // bf16 col: 0,8,16,24
    const short* BigS = (const short*)Big;
    size_t gbase0, gbase1;  // element offsets at k0=0
    if (MODE == 3) {
        int ma = m0 + grow, mb = m0 + grow + 16;
        gbase0 = ((size_t)((ma >> 11) * HH) * SS + (ma & 2047)) * HD;
        gbase1 = ((size_t)((mb >> 11) * HH) * SS + (mb & 2047)) * HD;
    } else {
        int r0 = ((MODE == 1) ? n0 : m0) + grow;
        gbase0 = (size_t)r0 * 1024 + gcol;
        gbase1 = gbase0 + (size_t)16 * 1024;
    }
    short* ldst0 = sBig + (wave << 10);  // wave-uniform LDS base
    short* ldst1 = ldst0 + 512;

    const int sml_base = (MODE == 1) ? m0 : n0;  // small operand tile rows

    v4f acc[4][4];
#pragma unroll
    for (int i = 0; i < 4; i++)
#pragma unroll
        for (int j = 0; j < 4; j++) acc[i][j] = v4f_zero();

    for (int k0 = 0; k0 < 1024; k0 += 32) {
        __syncthreads();
        // big operand: 2 x global_load_lds per wave (zero VALU, zero VGPR)
        if (MODE == 3) {
            size_t hoff = (size_t)(k0 >> 6) * (SS * HD) + (k0 & 63) + gcol;
            gll16(BigS + gbase0 + hoff, ldst0);
            gll16(BigS + gbase1 + hoff, ldst1);
        } else {
            gll16(BigS + gbase0 + k0, ldst0);
            gll16(BigS + gbase1 + k0, ldst1);
        }
        // small operand (weights, fp32, L2/L3-hot): reg-stage + cvt_pk
#pragma unroll
        for (int p = 0; p < 2; p++) {
            int idx = ((p << 8) + tid) << 3;
            int r = idx >> 5;
            int c = idx & 31;
            *(v8s*)&sSml[idx] =
                load8f(Sml + (size_t)(sml_base + r) * 1024 + k0 + c);
        }
        __syncthreads();

        v8s af[4], bfr[4];
#pragma unroll
        for (int i = 0; i < 4; i++)
            af[i] = *(const v8s*)&sA[(wm * 64 + i * 16 + l16) * 32 + quad * 8];
#pragma unroll
        for (int j = 0; j < 4; j++)
            bfr[j] = *(const v8s*)&sB[(wn * 64 + j * 16 + l16) * 32 + quad * 8];
#pragma unroll
        for (int i = 0; i < 4; i++)
#pragma unroll
            for (int j = 0; j < 4; j++)
                acc[i][j] = __builtin_amdgcn_mfma_f32_16x16x32_bf16(
                    af[i], bfr[j], acc[i][j], 0, 0, 0);
    }

    // Epilogue: C/D layout col = lane&15, row = quad*4 + reg (HW-verified r6)
#pragma unroll
    for (int i = 0; i < 4; i++) {
#pragma unroll
        for (int j = 0; j < 4; j++) {
#pragma unroll
            for (int r = 0; r < 4; r++) {
                int ml = wm * 64 + i * 16 + quad * 4 + r;
                int nl = wn * 64 + j * 16 + l16;
                int m = m0 + ml;
                int n = n0 + nl;
                float v = acc[i][j][r];
                if (MODE == 0) {
                    v += bias[n];
                    int b = m >> 11, s = m & 2047, h = n >> 6, d = n & 63;
                    ((short*)Cv)[(((size_t)(b * HH + h) * SS + s) << 6) + d] =
                        f2bf(v);
                } else if (MODE == 1) {
                    v += bias[m];
                    int h = m >> 6, d = m & 63, b = n >> 11, s = n & 2047;
                    ((short*)Cv)[((size_t)(b * HH + h) * HD + d) * SS + s] =
                        f2bf(v);
                } else {
                    v += bias[n];
                    ((float*)Cv)[(size_t)m * 1024 + n] = v;  // FP32 output
                }
            }
        }
    }
}

// ---------------------------------------------------------------------------
// Flash attention (causal, MFMA). Grid: (S/64 q-tiles, B*H). 256 thr = 4 waves.
// Unchanged from round 7 (196us): ones-MFMA softmax denominator, no
// mid-barrier (sP per-wave), setprio around MFMA clusters, reversed qt order.
// ---------------------------------------------------------------------------
__global__ __launch_bounds__(256) void attn_kernel(
    short* __restrict__ QO, const short* __restrict__ Kt,
    const short* __restrict__ Vt) {
    constexpr int LDR = 64 + 8;
    __shared__ short sK[64 * LDR];
    __shared__ short sV[64 * LDR];
    __shared__ short sP[4][16 * LDR];

    const int tid = threadIdx.x;
    const int lane = tid & 63;
    const int wave = tid >> 6;
    const int quad = lane >> 4;
    const int l16 = lane & 15;
    const int qt = (int)gridDim.x - 1 - (int)blockIdx.x;
    const int bh = blockIdx.y;

    short* Qh = QO + (size_t)bh * SS * HD;
    const short* Kh = Kt + (size_t)bh * SS * HD;
    const short* Vh = Vt + (size_t)bh * HD * SS;

    const int qrow = qt * 64 + wave * 16 + l16;
    v8s qf[2];
    qf[0] = *(const v8s*)&Qh[(size_t)qrow * HD + quad * 8];
    qf[1] = *(const v8s*)&Qh[(size_t)qrow * HD + 32 + quad * 8];

    v8s onesb;
#pragma unroll
    for (int i = 0; i < 8; i++) onesb[i] = (short)0x3F80;  // bf16 1.0

    v4f o[4];
#pragma unroll
    for (int j = 0; j < 4; j++) o[j] = v4f_zero();
    v4f oSum = v4f_zero();
    float mOld[4];
#pragma unroll
    for (int r = 0; r < 4; r++) mOld[r] = NEG_BIG;

    const int qg_base = qt * 64 + wave * 16 + quad * 4;

    for (int kt = 0; kt <= qt; kt++) {
        __syncthreads();
#pragma unroll
        for (int p = 0; p < 2; p++) {
            int idx = (p * 256 + tid) * 8;
            int r = idx >> 6;
            int c = idx & 63;
            *(v8s*)&sK[r * LDR + c] =
                *(const v8s*)&Kh[(size_t)(kt * 64 + r) * HD + c];
            *(v8s*)&sV[r * LDR + c] =
                *(const v8s*)&Vh[(size_t)r * SS + kt * 64 + c];
        }
        __syncthreads();

        __builtin_amdgcn_s_setprio(1);
        v4f sc[4];
#pragma unroll
        for (int j = 0; j < 4; j++) {
            v8s b0 = *(const v8s*)&sK[(j * 16 + l16) * LDR + quad * 8];
            v8s b1 = *(const v8s*)&sK[(j * 16 + l16) * LDR + 32 + quad * 8];
            v4f t = __builtin_amdgcn_mfma_f32_16x16x32_bf16(qf[0], b0,
                                                            v4f_zero(), 0, 0, 0);
            sc[j] = __builtin_amdgcn_mfma_f32_16x16x32_bf16(qf[1], b1, t, 0, 0, 0);
        }
        __builtin_amdgcn_s_setprio(0);

        float x[4][4];
        const bool diag = (kt == qt);
#pragma unroll
        for (int j = 0; j < 4; j++) {
#pragma unroll
            for (int r = 0; r < 4; r++) {
                float v = sc[j][r] * 0.125f;
                if (diag) {
                    int kg = kt * 64 + j * 16 + l16;
                    int qg = qg_base + r;
                    if (kg > qg) v = NEG_BIG;
                }
                x[j][r] = v;
            }
        }

        float mNew[4], alpha[4];
#pragma unroll
        for (int r = 0; r < 4; r++) {
            float t = fmaxf(fmaxf(x[0][r], x[1][r]), fmaxf(x[2][r], x[3][r]));
#pragma unroll
            for (int off = 8; off >= 1; off >>= 1) t = fmaxf(t, __shfl_xor(t, off));
            mNew[r] = fmaxf(mOld[r], t);
            alpha[r] = __expf(mOld[r] - mNew[r]);
            mOld[r] = mNew[r];
        }

        short* Pw = sP[wave];
#pragma unroll
        for (int j = 0; j < 4; j++)
#pragma unroll
            for (int r = 0; r < 4; r++) {
                float p = __expf(x[j][r] - mNew[r]);
                Pw[(quad * 4 + r) * LDR + j * 16 + l16] = f2bf(p);
            }
#pragma unroll
        for (int j = 0; j < 4; j++)
#pragma unroll
            for (int r = 0; r < 4; r++) o[j][r] *= alpha[r];
#pragma unroll
        for (int r = 0; r < 4; r++) oSum[r] *= alpha[r];

        v8s pa0 = *(const v8s*)&Pw[l16 * LDR + quad * 8];
        v8s pa1 = *(const v8s*)&Pw[l16 * LDR + 32 + quad * 8];
        __builtin_amdgcn_s_setprio(1);
#pragma unroll
        for (int j = 0; j < 4; j++) {
            v8s v0 = *(const v8s*)&sV[(j * 16 + l16) * LDR + quad * 8];
            v8s v1 = *(const v8s*)&sV[(j * 16 + l16) * LDR + 32 + quad * 8];
            o[j] = __builtin_amdgcn_mfma_f32_16x16x32_bf16(pa0, v0, o[j], 0, 0, 0);
            o[j] = __builtin_amdgcn_mfma_f32_16x16x32_bf16(pa1, v1, o[j], 0, 0, 0);
        }
        oSum = __builtin_amdgcn_mfma_f32_16x16x32_bf16(pa0, onesb, oSum, 0, 0, 0);
        oSum = __builtin_amdgcn_mfma_f32_16x16x32_bf16(pa1, onesb, oSum, 0, 0, 0);
        __builtin_amdgcn_s_setprio(0);
    }

#pragma unroll
    for (int r = 0; r < 4; r++) {
        float inv = 1.f / oSum[r];
        int s = qg_base + r;
#pragma unroll
        for (int j = 0; j < 4; j++) {
            float v = o[j][r] * inv;
            Qh[(size_t)s * HD + j * 16 + l16] = f2bf(v);
        }
    }
}

// ---------------------------------------------------------------------------
extern "C" void kernel_launch(void* const* d_in, const int* in_sizes, int n_in,
                              void* d_out, int out_size, void* d_ws, size_t ws_size,
                              hipStream_t stream) {
    const float* query = (const float*)d_in[0];
    const float* key_ = (const float*)d_in[1];
    const float* value = (const float*)d_in[2];
    const float* Wq = (const float*)d_in[3];
    const float* bq = (const float*)d_in[4];
    const float* Wk = (const float*)d_in[5];
    const float* bk = (const float*)d_in[6];
    const float* Wv = (const float*)d_in[7];
    const float* bv = (const float*)d_in[8];
    const float* Wo = (const float*)d_in[9];
    const float* bo = (const float*)d_in[10];
    float* out = (float*)d_out;

    const size_t NE = (size_t)BB * SS * DD;  // 8388608 elements

    // Memory plan (ws = 2*NE shorts verified; d_out = NE fp32 = 2*NE shorts):
    //   W0=ws[0:NE]   : qw (Q bf16; O in-place)      W1=ws[NE:2NE] : kw
    //   D0=dout[0:NE] : qx (tmp) -> vw (V^T home)    D1=dout[NE:2NE]: kx -> vx
    // Order guarantees each region is dead before reuse (stream-serialized).
    short* qx = (short*)d_out;
    short* kx = (short*)d_out + NE;
    short* vx = (short*)d_out + NE;
    short* vw = (short*)d_out;
    short* qw = (short*)d_ws;
    short* kw = (short*)d_ws + NE;

    dim3 blk(256);
    const int n8 = (int)(NE / 8);
    // 1) activations -> bf16
    conv_bf16_kernel<<<dim3(2048), blk, 0, stream>>>(query, qx, n8);
    conv_bf16_kernel<<<dim3(2048), blk, 0, stream>>>(key_, kx, n8);
    // 2) Q,K projections fused (z=0: Q, z=1: K); A via global_load_lds
    gemm_kernel<0><<<dim3(8, 64, 2), blk, 0, stream>>>(
        qx, Wq, bq, qw, kx, Wk, bk, kw);
    // 3) value -> bf16 (kx dead)
    conv_bf16_kernel<<<dim3(2048), blk, 0, stream>>>(value, vx, n8);
    // 4) V^T projection: big B = vx via global_load_lds; A = Wv fp32
    gemm_kernel<1><<<dim3(64, 8), blk, 0, stream>>>(
        vx, Wv, bv, vw, nullptr, nullptr, nullptr, nullptr);
    // 5) attention (O overwrites qw)
    attn_kernel<<<dim3(SS / 64, BB * HH), blk, 0, stream>>>(qw, kw, vw);
    // 6) out projection: A = O bf16 (remap) via global_load_lds; C fp32
    gemm_kernel<3><<<dim3(8, 64), blk, 0, stream>>>(
        qw, Wo, bo, out, nullptr, nullptr, nullptr, nullptr);
}